// Round 1
// baseline (529.418 us; speedup 1.0000x reference)
//
#include <hip/hip_runtime.h>

typedef unsigned short u16;
typedef __attribute__((ext_vector_type(8))) short short8;
typedef __attribute__((ext_vector_type(4))) float floatx4;
typedef __attribute__((ext_vector_type(4))) unsigned short ushort4_t;
typedef __attribute__((ext_vector_type(4))) float float4_t;

// ---- helpers ---------------------------------------------------------------

__device__ __forceinline__ u16 f2bf(float f) {
  unsigned u = __builtin_bit_cast(unsigned, f);
  u += 0x7FFFu + ((u >> 16) & 1u);   // round-to-nearest-even; inputs are finite
  return (u16)(u >> 16);
}

// async global->LDS, 16B per lane. LDS dest must be wave-uniform base + lane*16.
__device__ __forceinline__ void gload_lds16(const void* g, void* l) {
  __builtin_amdgcn_global_load_lds(
      (const __attribute__((address_space(1))) void*)g,
      (__attribute__((address_space(3))) void*)l, 16, 0, 0);
}

// ---- prep kernels ----------------------------------------------------------

// X fp32 [8192][1024] -> bf16, vectorized 4 elems/thread (exactly 8192 blocks x 256)
__global__ void cvt_x(const float* __restrict__ src, u16* __restrict__ dst) {
  int i = blockIdx.x * 256 + threadIdx.x;
  float4_t f = ((const float4_t*)src)[i];
  ushort4_t u;
  u.x = f2bf(f.x); u.y = f2bf(f.y); u.z = f2bf(f.z); u.w = f2bf(f.w);
  ((ushort4_t*)dst)[i] = u;
}

// W fp32 [1024][1024] row-major [K][N] -> bf16 transposed [N][K]
// (uncoalesced 4KB-stride reads; 4MB fits in one XCD L2, cost is a few us)
__global__ void transpose_cvt(const float* __restrict__ src, u16* __restrict__ dst) {
  int i = blockIdx.x * 256 + threadIdx.x;   // i = n*1024 + k
  int n = i >> 10, k = i & 1023;
  dst[i] = f2bf(src[k * 1024 + n]);
}

// ---- bf16 MFMA GEMM: C[m][n] = sum_k A[m][k] * Bt[n][k] --------------------
// 128x128 tile, BK=32, 256 threads = 4 waves (2x2 of 64x64), m97 structure.
// MODE 0: store bf16. MODE 1: store fp32 + bias[n].
template <int MODE>
__global__ __launch_bounds__(256) void gemm_bt(
    const u16* __restrict__ A, const u16* __restrict__ Bt, void* __restrict__ Cv,
    const float* __restrict__ bias, int K, int lda, int ldb, int ldc) {
  __shared__ u16 As[128 * 32];
  __shared__ u16 Bs[128 * 32];
  const int tid = threadIdx.x;
  const int w = tid >> 6, l = tid & 63, quad = l >> 4, l16 = l & 15;
  const int wm = w >> 1, wn = w & 1;
  const size_t m0 = (size_t)blockIdx.y * 128, n0 = (size_t)blockIdx.x * 128;

  floatx4 acc[4][4];
  for (int i = 0; i < 4; ++i)
    for (int j = 0; j < 4; ++j) acc[i][j] = (floatx4){0.f, 0.f, 0.f, 0.f};

  for (int k0 = 0; k0 < K; k0 += 32) {
    __syncthreads();  // previous tile's LDS reads complete
    for (int i = 0; i < 2; ++i) {
      int c = i * 256 + tid;              // 512 16B chunks per 8KB buffer
      int row = c >> 2, off = (c & 3) * 8;
      gload_lds16(A + (m0 + row) * (size_t)lda + k0 + off, &As[c * 8]);
      gload_lds16(Bt + (n0 + row) * (size_t)ldb + k0 + off, &Bs[c * 8]);
    }
    __syncthreads();  // barrier waits vmcnt(0): staging landed

    short8 a[4], bb[4];
    for (int im = 0; im < 4; ++im)
      a[im] = *(const short8*)&As[(wm * 64 + im * 16 + l16) * 32 + quad * 8];
    for (int in = 0; in < 4; ++in)
      bb[in] = *(const short8*)&Bs[(wn * 64 + in * 16 + l16) * 32 + quad * 8];
    for (int im = 0; im < 4; ++im)
      for (int in = 0; in < 4; ++in)
        acc[im][in] = __builtin_amdgcn_mfma_f32_16x16x32_bf16(a[im], bb[in], acc[im][in], 0, 0, 0);
  }

  // C/D layout: col = lane&15, row = quad*4 + reg
  for (int im = 0; im < 4; ++im)
    for (int in = 0; in < 4; ++in) {
      size_t r0 = m0 + wm * 64 + im * 16 + quad * 4;
      size_t col = n0 + wn * 64 + in * 16 + l16;
      float bv = (MODE == 1) ? bias[col] : 0.f;
      for (int r = 0; r < 4; ++r) {
        float val = acc[im][in][r] + bv;
        if (MODE == 0)
          ((u16*)Cv)[(r0 + r) * (size_t)ldc + col] = f2bf(val);
        else
          ((float*)Cv)[(r0 + r) * (size_t)ldc + col] = val;
      }
    }
}

// ---- flash attention (causal) ----------------------------------------------
// grid (32 q-tiles, 64 bh). 256 thr = 4 waves, wave w owns 16 query rows.
// Qb/Kb: bf16 [8192][1024] (row b*2048+n, col h*64+d). Vt: bf16 [1024][8192]
// (row h*64+d, col b*2048+n). ctx out: bf16 [8192][1024].
__global__ __launch_bounds__(256) void flash_attn(
    const u16* __restrict__ Qb, const u16* __restrict__ Kb,
    const u16* __restrict__ Vt, u16* __restrict__ ctx) {
  __shared__ u16 Ks[64 * 64];   // [kpos][d]
  __shared__ u16 Vs[64 * 64];   // [d][kpos]
  __shared__ u16 Ps[4 * 16 * 64];  // per-wave P round-trip (C-layout -> A-layout)

  const int tid = threadIdx.x;
  const int w = tid >> 6, l = tid & 63, quad = l >> 4, l16 = l & 15;
  const int qt = blockIdx.x, bh = blockIdx.y, b = bh >> 4, h = bh & 15;
  const int q0w = qt * 64 + w * 16;

  // Q A-fragments: lane holds Q[q0w + lane16][kk*32 + quad*8 + j]
  short8 aq[2];
  {
    const size_t base = ((size_t)(b * 2048 + q0w + l16)) * 1024 + h * 64 + quad * 8;
    aq[0] = *(const short8*)(Qb + base);
    aq[1] = *(const short8*)(Qb + base + 32);
  }

  floatx4 o[4];
  float mrow[4], lrow[4];
  for (int i = 0; i < 4; ++i) {
    o[i] = (floatx4){0.f, 0.f, 0.f, 0.f};
    mrow[i] = -1e30f;
    lrow[i] = 0.f;
  }

  u16* Psw = Ps + w * 1024;
  const float SC = 0.125f * 1.44269504088896340736f;  // 1/sqrt(64) * log2(e)

  for (int kt = 0; kt <= qt; ++kt) {
    __syncthreads();
    for (int i = 0; i < 2; ++i) {
      int c = i * 256 + tid;            // 512 chunks per 8KB tile
      int row = c >> 3, off = (c & 7) * 8;
      gload_lds16(Kb + ((size_t)(b * 2048 + kt * 64 + row)) * 1024 + h * 64 + off, &Ks[c * 8]);
      gload_lds16(Vt + ((size_t)(h * 64 + row)) * 8192 + b * 2048 + kt * 64 + off, &Vs[c * 8]);
    }
    __syncthreads();

    // S = Q K^T : 16x64 per wave, 8 MFMA
    floatx4 s[4];
    for (int nf = 0; nf < 4; ++nf) s[nf] = (floatx4){0.f, 0.f, 0.f, 0.f};
    for (int nf = 0; nf < 4; ++nf)
      for (int kk = 0; kk < 2; ++kk) {
        short8 bk = *(const short8*)&Ks[(nf * 16 + l16) * 64 + kk * 32 + quad * 8];
        s[nf] = __builtin_amdgcn_mfma_f32_16x16x32_bf16(aq[kk], bk, s[nf], 0, 0, 0);
      }

    // scale to log2 units; causal mask only needed on the diagonal tile
    if (kt == qt) {
      for (int nf = 0; nf < 4; ++nf)
        for (int r = 0; r < 4; ++r) {
          int qpos = q0w + quad * 4 + r;
          int kpos = kt * 64 + nf * 16 + l16;
          float t = s[nf][r] * SC;
          s[nf][r] = (kpos > qpos) ? -1e30f : t;
        }
    } else {
      for (int nf = 0; nf < 4; ++nf)
        for (int r = 0; r < 4; ++r) s[nf][r] = s[nf][r] * SC;
    }

    // row max over 64 cols: 4 frags in-lane, then 16-lane quad butterfly
    float rm[4];
    for (int r = 0; r < 4; ++r)
      rm[r] = fmaxf(fmaxf(s[0][r], s[1][r]), fmaxf(s[2][r], s[3][r]));
    for (int x = 1; x < 16; x <<= 1)
      for (int r = 0; r < 4; ++r) rm[r] = fmaxf(rm[r], __shfl_xor(rm[r], x, 64));

    float alpha[4];
    for (int r = 0; r < 4; ++r) {
      float mn = fmaxf(mrow[r], rm[r]);
      alpha[r] = exp2f(mrow[r] - mn);
      mrow[r] = mn;
    }
    float rs[4] = {0.f, 0.f, 0.f, 0.f};
    for (int nf = 0; nf < 4; ++nf)
      for (int r = 0; r < 4; ++r) {
        float p = exp2f(s[nf][r] - mrow[r]);
        s[nf][r] = p;
        rs[r] += p;
      }
    for (int x = 1; x < 16; x <<= 1)
      for (int r = 0; r < 4; ++r) rs[r] += __shfl_xor(rs[r], x, 64);
    for (int r = 0; r < 4; ++r) lrow[r] = lrow[r] * alpha[r] + rs[r];
    for (int df = 0; df < 4; ++df)
      for (int r = 0; r < 4; ++r) o[df][r] *= alpha[r];

    // P: C-layout regs -> LDS (bf16) -> A-layout frags
    for (int nf = 0; nf < 4; ++nf)
      for (int r = 0; r < 4; ++r)
        Psw[(quad * 4 + r) * 64 + nf * 16 + l16] = f2bf(s[nf][r]);

    for (int kk = 0; kk < 2; ++kk) {
      short8 ap = *(const short8*)&Psw[l16 * 64 + kk * 32 + quad * 8];
      for (int df = 0; df < 4; ++df) {
        short8 bv = *(const short8*)&Vs[(df * 16 + l16) * 64 + kk * 32 + quad * 8];
        o[df] = __builtin_amdgcn_mfma_f32_16x16x32_bf16(ap, bv, o[df], 0, 0, 0);
      }
    }
  }

  for (int df = 0; df < 4; ++df)
    for (int r = 0; r < 4; ++r) {
      float val = o[df][r] / lrow[r];
      size_t row = (size_t)(b * 2048 + q0w + quad * 4 + r);
      ctx[row * 1024 + h * 64 + df * 16 + l16] = f2bf(val);
    }
}

// ---- launch ----------------------------------------------------------------

extern "C" void kernel_launch(void* const* d_in, const int* in_sizes, int n_in,
                              void* d_out, int out_size, void* d_ws, size_t ws_size,
                              hipStream_t stream) {
  const float* X  = (const float*)d_in[0];
  const float* Wq = (const float*)d_in[1];
  const float* Wk = (const float*)d_in[2];
  const float* Wv = (const float*)d_in[3];
  const float* Wo = (const float*)d_in[4];
  const float* bo = (const float*)d_in[5];

  char* ws = (char*)d_ws;
  // workspace layout (72 MiB total)
  u16* Xb  = (u16*)(ws);                      // 16 MiB: Xb, later reused as ctx
  u16* WqT = (u16*)(ws + (16u << 20));        // 2 MiB each
  u16* WkT = (u16*)(ws + (18u << 20));
  u16* WvT = (u16*)(ws + (20u << 20));
  u16* WoT = (u16*)(ws + (22u << 20));
  u16* Qb  = (u16*)(ws + (24u << 20));        // 16 MiB
  u16* Kb  = (u16*)(ws + (40u << 20));        // 16 MiB
  u16* Vt  = (u16*)(ws + (56u << 20));        // 16 MiB, [h*64+d][b*2048+n]

  cvt_x<<<8192, 256, 0, stream>>>(X, Xb);
  transpose_cvt<<<4096, 256, 0, stream>>>(Wq, WqT);
  transpose_cvt<<<4096, 256, 0, stream>>>(Wk, WkT);
  transpose_cvt<<<4096, 256, 0, stream>>>(Wv, WvT);
  transpose_cvt<<<4096, 256, 0, stream>>>(Wo, WoT);

  // Q = Xb @ Wq   : [8192][1024]
  gemm_bt<0><<<dim3(8, 64), 256, 0, stream>>>(Xb, WqT, Qb, nullptr, 1024, 1024, 1024, 1024);
  // K = Xb @ Wk   : [8192][1024]
  gemm_bt<0><<<dim3(8, 64), 256, 0, stream>>>(Xb, WkT, Kb, nullptr, 1024, 1024, 1024, 1024);
  // Vt = (Xb @ Wv)^T computed directly: C[hd][bn] = sum_k WvT[hd][k]*Xb[bn][k]
  gemm_bt<0><<<dim3(64, 8), 256, 0, stream>>>(WvT, Xb, Vt, nullptr, 1024, 1024, 1024, 8192);

  // causal flash attention; ctx overwrites Xb (dead after V projection)
  flash_attn<<<dim3(32, 64), 256, 0, stream>>>(Qb, Kb, Vt, Xb);

  // out = ctx @ Wo + bo : fp32
  gemm_bt<1><<<dim3(8, 64), 256, 0, stream>>>(Xb, WoT, (float*)d_out, bo, 1024, 1024, 1024, 1024);
}

// Round 2
// 287.515 us; speedup vs baseline: 1.8414x; 1.8414x over previous
//
#include <hip/hip_runtime.h>

typedef unsigned short u16;
typedef unsigned int u32;
typedef __attribute__((ext_vector_type(8))) short short8;
typedef __attribute__((ext_vector_type(4))) float floatx4;
typedef __attribute__((ext_vector_type(4))) unsigned short ushort4_t;
typedef __attribute__((ext_vector_type(4))) float float4_t;
typedef __attribute__((ext_vector_type(2))) unsigned int uint2_t;

// ---- helpers ---------------------------------------------------------------

__device__ __forceinline__ u16 f2bf(float f) {
  unsigned u = __builtin_bit_cast(unsigned, f);
  u += 0x7FFFu + ((u >> 16) & 1u);   // RNE; inputs finite
  return (u16)(u >> 16);
}

// pack two fp32 -> bf16x2 (round-to-nearest, no tie-even): hi = a, lo = b
__device__ __forceinline__ u32 pack_bf2(float a, float b) {
  u32 ua = __builtin_bit_cast(u32, a) + 0x8000u;
  u32 ub = __builtin_bit_cast(u32, b) + 0x8000u;
  return __builtin_amdgcn_perm(ua, ub, 0x07060302u);  // [a.hi16 : b.hi16]
}

// async global->LDS, 16B per lane. LDS dest must be wave-uniform base + lane*16.
__device__ __forceinline__ void gload_lds16(const void* g, void* l) {
  __builtin_amdgcn_global_load_lds(
      (const __attribute__((address_space(1))) void*)g,
      (__attribute__((address_space(3))) void*)l, 16, 0, 0);
}

// ---- prep kernels ----------------------------------------------------------

// X fp32 [8192][1024] -> bf16
__global__ void cvt_x(const float* __restrict__ src, u16* __restrict__ dst) {
  int i = blockIdx.x * 256 + threadIdx.x;
  float4_t f = ((const float4_t*)src)[i];
  ushort4_t u;
  u.x = f2bf(f.x); u.y = f2bf(f.y); u.z = f2bf(f.z); u.w = f2bf(f.w);
  ((ushort4_t*)dst)[i] = u;
}

// all 4 weights fp32 [K][N] -> bf16 [N][K]; Wq gets the softmax scale folded in.
__global__ void transpose_cvt4(const float* __restrict__ wq, const float* __restrict__ wk,
                               const float* __restrict__ wv, const float* __restrict__ wo,
                               u16* __restrict__ qk, u16* __restrict__ vt,
                               u16* __restrict__ ot, float sc) {
  int i = blockIdx.x * 256 + threadIdx.x;   // i = n*1024 + k
  int n = i >> 10, k = i & 1023;
  int which = blockIdx.y;
  const float* s = (which == 0) ? wq : (which == 1) ? wk : (which == 2) ? wv : wo;
  u16* d = (which == 0) ? qk : (which == 1) ? (qk + (1u << 20)) : (which == 2) ? vt : ot;
  float f = s[k * 1024 + n] * ((which == 0) ? sc : 1.f);
  d[i] = f2bf(f);
}

// ---- bf16 MFMA GEMM: C[m][n] = sum_k A[m][k] * Bt[n][k] --------------------
// MODE 0: store bf16. MODE 1: store fp32 + bias[n].
template <int MODE>
__global__ __launch_bounds__(256) void gemm_bt(
    const u16* __restrict__ A, const u16* __restrict__ Bt, void* __restrict__ Cv,
    const float* __restrict__ bias, int K, int lda, int ldb, int ldc) {
  __shared__ u16 As[128 * 32];
  __shared__ u16 Bs[128 * 32];
  const int tid = threadIdx.x;
  const int w = tid >> 6, l = tid & 63, quad = l >> 4, l16 = l & 15;
  const int wm = w >> 1, wn = w & 1;
  const size_t m0 = (size_t)blockIdx.y * 128, n0 = (size_t)blockIdx.x * 128;

  floatx4 acc[4][4];
  for (int i = 0; i < 4; ++i)
    for (int j = 0; j < 4; ++j) acc[i][j] = (floatx4){0.f, 0.f, 0.f, 0.f};

  for (int k0 = 0; k0 < K; k0 += 32) {
    __syncthreads();
    for (int i = 0; i < 2; ++i) {
      int c = i * 256 + tid;
      int row = c >> 2, off = (c & 3) * 8;
      gload_lds16(A + (m0 + row) * (size_t)lda + k0 + off, &As[c * 8]);
      gload_lds16(Bt + (n0 + row) * (size_t)ldb + k0 + off, &Bs[c * 8]);
    }
    __syncthreads();

    short8 a[4], bb[4];
    for (int im = 0; im < 4; ++im)
      a[im] = *(const short8*)&As[(wm * 64 + im * 16 + l16) * 32 + quad * 8];
    for (int in = 0; in < 4; ++in)
      bb[in] = *(const short8*)&Bs[(wn * 64 + in * 16 + l16) * 32 + quad * 8];
    for (int im = 0; im < 4; ++im)
      for (int in = 0; in < 4; ++in)
        acc[im][in] = __builtin_amdgcn_mfma_f32_16x16x32_bf16(a[im], bb[in], acc[im][in], 0, 0, 0);
  }

  for (int im = 0; im < 4; ++im)
    for (int in = 0; in < 4; ++in) {
      size_t r0 = m0 + wm * 64 + im * 16 + quad * 4;
      size_t col = n0 + wn * 64 + in * 16 + l16;
      float bv = (MODE == 1) ? bias[col] : 0.f;
      for (int r = 0; r < 4; ++r) {
        float val = acc[im][in][r] + bv;
        if (MODE == 0)
          ((u16*)Cv)[(r0 + r) * (size_t)ldc + col] = f2bf(val);
        else
          ((float*)Cv)[(r0 + r) * (size_t)ldc + col] = val;
      }
    }
}

// ---- flash attention (causal, S^T form, no-max softmax) --------------------
// grid (64 bh, 16 qt desc). 256 thr = 4 waves; wave owns 32 q (2 x 16 frags).
// QK: bf16 [8192][2048] (Q cols 0..1023 pre-scaled, K cols 1024..2047).
// Vt: bf16 [1024][8192]. ctx: bf16 [8192][1024].
// LDS tiles use 16B-chunk XOR swizzle: byte(row,col) = row*128 + ((2*col) ^ ((row&7)<<4)).
__global__ __launch_bounds__(256) void flash_attn(
    const u16* __restrict__ QK, const u16* __restrict__ Vt, u16* __restrict__ ctx) {
  __shared__ u16 Ks[64 * 64];      // [kpos][d]   swizzled
  __shared__ u16 Vs[64 * 64];      // [d][kpos]   swizzled
  __shared__ u16 Ps[4 * 16 * 64];  // per-wave [q16][kpos] swizzled
  __shared__ float Ls[4 * 32];     // per-wave 1/rowsum

  const int tid = threadIdx.x;
  const int w = tid >> 6, l = tid & 63, quad = l >> 4, l16 = l & 15;
  const int bh = blockIdx.x, qt = 15 - (int)blockIdx.y;  // longest blocks first
  const int b = bh >> 4, h = bh & 15;
  const int q0w = qt * 128 + w * 32;
  const int nkt = 2 * qt + 2;
  const int xr = (l16 & 7) << 4;

  // Q B-frags (scale pre-folded into Wq): aq[qf][kk]
  short8 aq[2][2];
  for (int qf = 0; qf < 2; ++qf) {
    const size_t base = (size_t)(b * 2048 + q0w + qf * 16 + l16) * 2048 + h * 64 + quad * 8;
    aq[qf][0] = *(const short8*)(QK + base);
    aq[qf][1] = *(const short8*)(QK + base + 32);
  }

  floatx4 o[2][4];
  float lsum[2] = {0.f, 0.f};
  for (int qf = 0; qf < 2; ++qf)
    for (int df = 0; df < 4; ++df) o[qf][df] = (floatx4){0.f, 0.f, 0.f, 0.f};

  char* Psw = (char*)Ps + w * 2048;

  for (int kt = 0; kt < nkt; ++kt) {
    __syncthreads();
    for (int i = 0; i < 2; ++i) {
      int c = i * 256 + tid;
      int row = c >> 3, scol = ((c & 7) ^ (row & 7)) << 3;  // swizzled global col
      gload_lds16(QK + (size_t)(b * 2048 + kt * 64 + row) * 2048 + 1024 + h * 64 + scol,
                  &Ks[c * 8]);
      gload_lds16(Vt + (size_t)(h * 64 + row) * 8192 + b * 2048 + kt * 64 + scol,
                  &Vs[c * 8]);
    }
    __syncthreads();

    if (kt * 64 > q0w + 31) continue;               // wave fully masked (uniform)
    const bool need_mask = (kt * 64 + 63) > q0w;

    // K A-frags: ka[nf][kk] — row = nf*16+l16
    short8 ka[4][2];
    for (int nf = 0; nf < 4; ++nf) {
      const char* kb = (const char*)Ks + (nf * 16 + l16) * 128;
      ka[nf][0] = *(const short8*)(kb + ((quad * 16) ^ xr));
      ka[nf][1] = *(const short8*)(kb + ((64 + quad * 16) ^ xr));
    }

    for (int qf = 0; qf < 2; ++qf) {
      // S^T[kpos][q]: col = q = l16, row = kpos = nf*16 + quad*4 + r
      floatx4 s[4];
      for (int nf = 0; nf < 4; ++nf) s[nf] = (floatx4){0.f, 0.f, 0.f, 0.f};
      for (int nf = 0; nf < 4; ++nf) {
        s[nf] = __builtin_amdgcn_mfma_f32_16x16x32_bf16(ka[nf][0], aq[qf][0], s[nf], 0, 0, 0);
        s[nf] = __builtin_amdgcn_mfma_f32_16x16x32_bf16(ka[nf][1], aq[qf][1], s[nf], 0, 0, 0);
      }
      if (need_mask) {
        int qpos = q0w + qf * 16 + l16;
        for (int nf = 0; nf < 4; ++nf)
          for (int r = 0; r < 4; ++r) {
            int kpos = kt * 64 + nf * 16 + quad * 4 + r;
            if (kpos > qpos) s[nf][r] = -1e30f;
          }
      }
      // p = exp2(s); accumulate per-lane row partials; pack to Ps (bf16)
      for (int nf = 0; nf < 4; ++nf) {
        float p0 = __builtin_amdgcn_exp2f(s[nf][0]);
        float p1 = __builtin_amdgcn_exp2f(s[nf][1]);
        float p2 = __builtin_amdgcn_exp2f(s[nf][2]);
        float p3 = __builtin_amdgcn_exp2f(s[nf][3]);
        lsum[qf] += (p0 + p1) + (p2 + p3);
        uint2_t pk;
        pk.x = pack_bf2(p1, p0);
        pk.y = pack_bf2(p3, p2);
        *(uint2_t*)(Psw + l16 * 128 + ((nf * 32 + quad * 8) ^ xr)) = pk;
      }
      // o[q][d] += P x V : A = Ps row l16, B = Vs rows df*16+l16
      for (int kk = 0; kk < 2; ++kk) {
        short8 ap = *(const short8*)(Psw + l16 * 128 + ((kk * 64 + quad * 16) ^ xr));
        for (int df = 0; df < 4; ++df) {
          const char* vb = (const char*)Vs + (df * 16 + l16) * 128;
          short8 bv = *(const short8*)(vb + ((kk * 64 + quad * 16) ^ xr));
          o[qf][df] = __builtin_amdgcn_mfma_f32_16x16x32_bf16(ap, bv, o[qf][df], 0, 0, 0);
        }
      }
    }
  }

  // deferred row-sum: cross-quad reduce, then per-wave LDS broadcast of 1/l
  for (int qf = 0; qf < 2; ++qf) {
    float t = lsum[qf];
    t += __shfl_xor(t, 16, 64);
    t += __shfl_xor(t, 32, 64);
    if (l < 16) Ls[w * 32 + qf * 16 + l16] = __builtin_amdgcn_rcpf(t);
  }
  for (int qf = 0; qf < 2; ++qf) {
    floatx4 inv = *(const floatx4*)&Ls[w * 32 + qf * 16 + quad * 4];
    for (int df = 0; df < 4; ++df)
      for (int r = 0; r < 4; ++r) {
        float val = o[qf][df][r] * inv[r];
        size_t row = (size_t)(b * 2048 + q0w + qf * 16 + quad * 4 + r);
        ctx[row * 1024 + h * 64 + df * 16 + l16] = f2bf(val);
      }
  }
}

// ---- launch ----------------------------------------------------------------

extern "C" void kernel_launch(void* const* d_in, const int* in_sizes, int n_in,
                              void* d_out, int out_size, void* d_ws, size_t ws_size,
                              hipStream_t stream) {
  const float* X  = (const float*)d_in[0];
  const float* Wq = (const float*)d_in[1];
  const float* Wk = (const float*)d_in[2];
  const float* Wv = (const float*)d_in[3];
  const float* Wo = (const float*)d_in[4];
  const float* bo = (const float*)d_in[5];

  char* ws = (char*)d_ws;
  u16* Xb   = (u16*)(ws);                  // 16 MiB; later overwritten with ctx
  u16* WqkT = (u16*)(ws + (16u << 20));    // 4 MiB: [Wq^T(scaled) ; Wk^T] = [2048][1024]
  u16* WvT  = (u16*)(ws + (20u << 20));    // 2 MiB
  u16* WoT  = (u16*)(ws + (22u << 20));    // 2 MiB
  u16* QKb  = (u16*)(ws + (24u << 20));    // 32 MiB: [8192][2048]
  u16* Vt   = (u16*)(ws + (56u << 20));    // 16 MiB: [1024][8192]

  const float SC = 0.125f * 1.44269504088896340736f;  // 1/sqrt(64) * log2(e)

  cvt_x<<<8192, 256, 0, stream>>>(X, Xb);
  transpose_cvt4<<<dim3(4096, 4), 256, 0, stream>>>(Wq, Wk, Wv, Wo, WqkT, WvT, WoT, SC);

  // [Q K] = Xb @ [Wq Wk] : [8192][2048]
  gemm_bt<0><<<dim3(16, 64), 256, 0, stream>>>(Xb, WqkT, QKb, nullptr, 1024, 1024, 1024, 2048);
  // Vt = (Xb @ Wv)^T : [1024][8192]
  gemm_bt<0><<<dim3(64, 8), 256, 0, stream>>>(WvT, Xb, Vt, nullptr, 1024, 1024, 1024, 8192);

  // causal flash attention; ctx overwrites Xb
  flash_attn<<<dim3(64, 16), 256, 0, stream>>>(QKb, Vt, Xb);

  // out = ctx @ Wo + bo : fp32
  gemm_bt<1><<<dim3(8, 64), 256, 0, stream>>>(Xb, WoT, (float*)d_out, bo, 1024, 1024, 1024, 1024);
}

// Round 3
// 268.761 us; speedup vs baseline: 1.9698x; 1.0698x over previous
//
#include <hip/hip_runtime.h>

typedef unsigned short u16;
typedef unsigned int u32;
typedef __attribute__((ext_vector_type(8))) short short8;
typedef __attribute__((ext_vector_type(4))) float floatx4;
typedef __attribute__((ext_vector_type(4))) unsigned short ushort4_t;
typedef __attribute__((ext_vector_type(4))) float float4_t;
typedef __attribute__((ext_vector_type(2))) unsigned int uint2_t;

// ---- helpers ---------------------------------------------------------------

__device__ __forceinline__ u16 f2bf(float f) {
  unsigned u = __builtin_bit_cast(unsigned, f);
  u += 0x7FFFu + ((u >> 16) & 1u);   // RNE; inputs finite
  return (u16)(u >> 16);
}

// pack two fp32 -> bf16x2: lo16 = b, hi16 = a (memory order b, a)
__device__ __forceinline__ u32 pack_bf2(float a, float b) {
  u32 ua = __builtin_bit_cast(u32, a) + 0x8000u;
  u32 ub = __builtin_bit_cast(u32, b) + 0x8000u;
  return __builtin_amdgcn_perm(ua, ub, 0x07060302u);
}

// async global->LDS, 16B per lane. LDS dest must be wave-uniform base + lane*16.
__device__ __forceinline__ void gload_lds16(const void* g, void* l) {
  __builtin_amdgcn_global_load_lds(
      (const __attribute__((address_space(1))) void*)g,
      (__attribute__((address_space(3))) void*)l, 16, 0, 0);
}

// ---- prep kernels ----------------------------------------------------------

// X fp32 [8192][1024] -> bf16
__global__ void cvt_x(const float* __restrict__ src, u16* __restrict__ dst) {
  int i = blockIdx.x * 256 + threadIdx.x;
  float4_t f = ((const float4_t*)src)[i];
  ushort4_t u;
  u.x = f2bf(f.x); u.y = f2bf(f.y); u.z = f2bf(f.z); u.w = f2bf(f.w);
  ((ushort4_t*)dst)[i] = u;
}

// coalesced LDS-tiled transpose+cvt: W fp32 [K][N] -> bf16 [N][K].
// grid (16,16,4): 64x64 tile per block; z selects the weight.
__global__ __launch_bounds__(256) void transpose_cvt4(
    const float* __restrict__ wq, const float* __restrict__ wk,
    const float* __restrict__ wv, const float* __restrict__ wo,
    u16* __restrict__ qk, u16* __restrict__ vt, u16* __restrict__ ot, float sc) {
  __shared__ float T[64][65];
  const int which = blockIdx.z;
  const float* s = (which == 0) ? wq : (which == 1) ? wk : (which == 2) ? wv : wo;
  u16* d = (which == 0) ? qk : (which == 1) ? (qk + (1u << 20)) : (which == 2) ? vt : ot;
  const float scale = (which == 0) ? sc : 1.f;
  const int n0 = blockIdx.x * 64, k0 = blockIdx.y * 64;
  const int c = threadIdx.x & 63, rg = threadIdx.x >> 6;
  for (int i = 0; i < 16; ++i) {
    int r = i * 4 + rg;
    T[r][c] = s[(k0 + r) * 1024 + n0 + c];          // coalesced 256B rows
  }
  __syncthreads();
  for (int i = 0; i < 16; ++i) {
    int r = i * 4 + rg;
    d[(n0 + r) * 1024 + k0 + c] = f2bf(T[c][r] * scale);  // coalesced 128B rows
  }
}

// ---- bf16 MFMA GEMM: C[m][n] = sum_k A[m][k] * Bt[n][k] --------------------
// 128x128 tile, BK=32, dbuf LDS with single end-of-iter barrier (prefetch
// latency overlaps compute). MODE 0: store bf16. MODE 1: fp32 + bias[n].
template <int MODE>
__global__ __launch_bounds__(256) void gemm_bt(
    const u16* __restrict__ A, const u16* __restrict__ Bt, void* __restrict__ Cv,
    const float* __restrict__ bias, int K, int lda, int ldb, int ldc) {
  __shared__ u16 As[2][128 * 32];
  __shared__ u16 Bs[2][128 * 32];
  const int tid = threadIdx.x;
  const int w = tid >> 6, l = tid & 63, quad = l >> 4, l16 = l & 15;
  const int wm = w >> 1, wn = w & 1;
  const size_t m0 = (size_t)blockIdx.y * 128, n0 = (size_t)blockIdx.x * 128;

  floatx4 acc[4][4];
  for (int i = 0; i < 4; ++i)
    for (int j = 0; j < 4; ++j) acc[i][j] = (floatx4){0.f, 0.f, 0.f, 0.f};

  auto stage = [&](int k0, int buf) {
    for (int i = 0; i < 2; ++i) {
      int c = i * 256 + tid;
      int row = c >> 2, off = (c & 3) * 8;
      gload_lds16(A + (m0 + row) * (size_t)lda + k0 + off, &As[buf][c * 8]);
      gload_lds16(Bt + (n0 + row) * (size_t)ldb + k0 + off, &Bs[buf][c * 8]);
    }
  };

  const int nk = K >> 5;
  stage(0, 0);
  __syncthreads();

  for (int ki = 0; ki < nk; ++ki) {
    const int buf = ki & 1;
    if (ki + 1 < nk) stage((ki + 1) << 5, buf ^ 1);

    short8 a[4], bb[4];
    for (int im = 0; im < 4; ++im)
      a[im] = *(const short8*)&As[buf][(wm * 64 + im * 16 + l16) * 32 + quad * 8];
    for (int in = 0; in < 4; ++in)
      bb[in] = *(const short8*)&Bs[buf][(wn * 64 + in * 16 + l16) * 32 + quad * 8];
    for (int im = 0; im < 4; ++im)
      for (int in = 0; in < 4; ++in)
        acc[im][in] = __builtin_amdgcn_mfma_f32_16x16x32_bf16(a[im], bb[in], acc[im][in], 0, 0, 0);

    __syncthreads();   // drains prefetch AFTER compute; also protects buf reuse
  }

  for (int im = 0; im < 4; ++im)
    for (int in = 0; in < 4; ++in) {
      size_t r0 = m0 + wm * 64 + im * 16 + quad * 4;
      size_t col = n0 + wn * 64 + in * 16 + l16;
      float bv = (MODE == 1) ? bias[col] : 0.f;
      for (int r = 0; r < 4; ++r) {
        float val = acc[im][in][r] + bv;
        if (MODE == 0)
          ((u16*)Cv)[(r0 + r) * (size_t)ldc + col] = f2bf(val);
        else
          ((float*)Cv)[(r0 + r) * (size_t)ldc + col] = val;
      }
    }
}

// ---- flash attention (causal, S^T form, no-max softmax, dbuf) --------------
// grid (64 bh, 16 qt desc). 256 thr = 4 waves; wave owns 32 q (2 x 16 frags).
// QK: bf16 [8192][2048] (Q pre-scaled cols 0..1023, K cols 1024..2047).
// Vt: bf16 [1024][8192]. ctx: bf16 [8192][1024].
// Swizzle: byte(row,col) = row*128 + ((2*col) ^ ((row&7)<<4)).
__global__ __launch_bounds__(256) void flash_attn(
    const u16* __restrict__ QK, const u16* __restrict__ Vt, u16* __restrict__ ctx) {
  __shared__ u16 Ks[2][64 * 64];
  __shared__ u16 Vs[2][64 * 64];
  __shared__ u16 Ps[4 * 16 * 64];
  __shared__ float Ls[128];

  const int tid = threadIdx.x;
  const int w = tid >> 6, l = tid & 63, quad = l >> 4, l16 = l & 15;
  const int bh = blockIdx.x, qt = 15 - (int)blockIdx.y;  // longest first
  const int b = bh >> 4, h = bh & 15;
  const int q0w = qt * 128 + w * 32;
  const int nkt = 2 * qt + 2;
  const int ktmax_w = (q0w + 31) >> 6;   // last live tile for this wave
  const int xr = (l16 & 7) << 4;

  auto stage = [&](int kt, int buf) {
    for (int i = 0; i < 2; ++i) {
      int c = i * 256 + tid;
      int row = c >> 3, scol = ((c & 7) ^ (row & 7)) << 3;
      gload_lds16(QK + (size_t)(b * 2048 + kt * 64 + row) * 2048 + 1024 + h * 64 + scol,
                  &Ks[buf][c * 8]);
      gload_lds16(Vt + (size_t)(h * 64 + row) * 8192 + b * 2048 + kt * 64 + scol,
                  &Vs[buf][c * 8]);
    }
  };

  // Q B-frags (softmax scale pre-folded into Wq)
  short8 aq[2][2];
  for (int qf = 0; qf < 2; ++qf) {
    const size_t base = (size_t)(b * 2048 + q0w + qf * 16 + l16) * 2048 + h * 64 + quad * 8;
    aq[qf][0] = *(const short8*)(QK + base);
    aq[qf][1] = *(const short8*)(QK + base + 32);
  }

  floatx4 o[2][4];
  float lsum[2] = {0.f, 0.f};
  for (int qf = 0; qf < 2; ++qf)
    for (int df = 0; df < 4; ++df) o[qf][df] = (floatx4){0.f, 0.f, 0.f, 0.f};

  char* Psw = (char*)Ps + w * 2048;

  stage(0, 0);
  __syncthreads();

  for (int kt = 0; kt < nkt; ++kt) {
    const int buf = kt & 1;
    if (kt + 1 < nkt) stage(kt + 1, buf ^ 1);   // prefetch overlaps compute below

    if (kt <= ktmax_w) {
      const bool need_mask = (kt == ktmax_w);

      short8 ka[4][2], bv[4][2];
      for (int nf = 0; nf < 4; ++nf) {
        const char* kb = (const char*)&Ks[buf][0] + (nf * 16 + l16) * 128;
        ka[nf][0] = *(const short8*)(kb + ((quad * 16) ^ xr));
        ka[nf][1] = *(const short8*)(kb + ((64 + quad * 16) ^ xr));
      }
      for (int df = 0; df < 4; ++df) {
        const char* vb = (const char*)&Vs[buf][0] + (df * 16 + l16) * 128;
        bv[df][0] = *(const short8*)(vb + ((quad * 16) ^ xr));
        bv[df][1] = *(const short8*)(vb + ((64 + quad * 16) ^ xr));
      }

      for (int qf = 0; qf < 2; ++qf) {
        floatx4 s[4];
        for (int nf = 0; nf < 4; ++nf) s[nf] = (floatx4){0.f, 0.f, 0.f, 0.f};
        for (int nf = 0; nf < 4; ++nf) {
          s[nf] = __builtin_amdgcn_mfma_f32_16x16x32_bf16(ka[nf][0], aq[qf][0], s[nf], 0, 0, 0);
          s[nf] = __builtin_amdgcn_mfma_f32_16x16x32_bf16(ka[nf][1], aq[qf][1], s[nf], 0, 0, 0);
        }
        if (need_mask) {
          int qpos = q0w + qf * 16 + l16;
          for (int nf = 0; nf < 4; ++nf)
            for (int r = 0; r < 4; ++r) {
              int kpos = kt * 64 + nf * 16 + quad * 4 + r;
              if (kpos > qpos) s[nf][r] = -1e30f;
            }
        }
        for (int nf = 0; nf < 4; ++nf) {
          float p0 = __builtin_amdgcn_exp2f(s[nf][0]);
          float p1 = __builtin_amdgcn_exp2f(s[nf][1]);
          float p2 = __builtin_amdgcn_exp2f(s[nf][2]);
          float p3 = __builtin_amdgcn_exp2f(s[nf][3]);
          lsum[qf] += (p0 + p1) + (p2 + p3);
          uint2_t pk;
          pk.x = pack_bf2(p1, p0);
          pk.y = pack_bf2(p3, p2);
          *(uint2_t*)(Psw + l16 * 128 + ((nf * 32 + quad * 8) ^ xr)) = pk;
        }
        for (int kk = 0; kk < 2; ++kk) {
          short8 ap = *(const short8*)(Psw + l16 * 128 + ((kk * 64 + quad * 16) ^ xr));
          for (int df = 0; df < 4; ++df)
            o[qf][df] = __builtin_amdgcn_mfma_f32_16x16x32_bf16(ap, bv[df][kk], o[qf][df], 0, 0, 0);
        }
      }
    }
    __syncthreads();   // drains prefetch AFTER compute; protects buf reuse
  }

  // row-sum transpose: lsum has q on lane axis; o has q on reg axis
  for (int qf = 0; qf < 2; ++qf) {
    float t = lsum[qf];
    t += __shfl_xor(t, 16, 64);
    t += __shfl_xor(t, 32, 64);
    if (l < 16) Ls[w * 32 + qf * 16 + l16] = __builtin_amdgcn_rcpf(t);
  }
  for (int qf = 0; qf < 2; ++qf) {
    floatx4 inv = *(const floatx4*)&Ls[w * 32 + qf * 16 + quad * 4];
    for (int df = 0; df < 4; ++df)
      for (int r = 0; r < 4; ++r) {
        float val = o[qf][df][r] * inv[r];
        size_t row = (size_t)(b * 2048 + q0w + qf * 16 + quad * 4 + r);
        ctx[row * 1024 + h * 64 + df * 16 + l16] = f2bf(val);
      }
  }
}

// ---- launch ----------------------------------------------------------------

extern "C" void kernel_launch(void* const* d_in, const int* in_sizes, int n_in,
                              void* d_out, int out_size, void* d_ws, size_t ws_size,
                              hipStream_t stream) {
  const float* X  = (const float*)d_in[0];
  const float* Wq = (const float*)d_in[1];
  const float* Wk = (const float*)d_in[2];
  const float* Wv = (const float*)d_in[3];
  const float* Wo = (const float*)d_in[4];
  const float* bo = (const float*)d_in[5];

  char* ws = (char*)d_ws;
  u16* Xb   = (u16*)(ws);                  // 16 MiB; later overwritten with ctx
  u16* WqkT = (u16*)(ws + (16u << 20));    // 4 MiB: [Wq^T(scaled) ; Wk^T]
  u16* WvT  = (u16*)(ws + (20u << 20));    // 2 MiB
  u16* WoT  = (u16*)(ws + (22u << 20));    // 2 MiB
  u16* QKb  = (u16*)(ws + (24u << 20));    // 32 MiB: [8192][2048]
  u16* Vt   = (u16*)(ws + (56u << 20));    // 16 MiB: [1024][8192]

  const float SC = 0.125f * 1.44269504088896340736f;  // 1/sqrt(64) * log2(e)

  cvt_x<<<8192, 256, 0, stream>>>(X, Xb);
  transpose_cvt4<<<dim3(16, 16, 4), 256, 0, stream>>>(Wq, Wk, Wv, Wo, WqkT, WvT, WoT, SC);

  // [Q K] = Xb @ [Wq Wk] : [8192][2048]
  gemm_bt<0><<<dim3(16, 64), 256, 0, stream>>>(Xb, WqkT, QKb, nullptr, 1024, 1024, 1024, 2048);
  // Vt = (Xb @ Wv)^T : [1024][8192]
  gemm_bt<0><<<dim3(64, 8), 256, 0, stream>>>(WvT, Xb, Vt, nullptr, 1024, 1024, 1024, 8192);

  // causal flash attention; ctx overwrites Xb
  flash_attn<<<dim3(64, 16), 256, 0, stream>>>(QKb, Vt, Xb);

  // out = ctx @ Wo + bo : fp32
  gemm_bt<1><<<dim3(8, 64), 256, 0, stream>>>(Xb, WoT, (float*)d_out, bo, 1024, 1024, 1024, 1024);
}

// Round 4
// 261.472 us; speedup vs baseline: 2.0248x; 1.0279x over previous
//
#include <hip/hip_runtime.h>

typedef unsigned short u16;
typedef unsigned int u32;
typedef __attribute__((ext_vector_type(8))) short short8;
typedef __attribute__((ext_vector_type(4))) short short4_t;
typedef __attribute__((ext_vector_type(4))) float floatx4;
typedef __attribute__((ext_vector_type(4))) unsigned short ushort4_t;
typedef __attribute__((ext_vector_type(4))) float float4_t;
typedef __attribute__((ext_vector_type(2))) unsigned int uint2_t;

// ---- helpers ---------------------------------------------------------------

__device__ __forceinline__ u16 f2bf(float f) {
  unsigned u = __builtin_bit_cast(unsigned, f);
  u += 0x7FFFu + ((u >> 16) & 1u);   // RNE; inputs finite
  return (u16)(u >> 16);
}

// pack two fp32 -> bf16x2: lo16 = b, hi16 = a
__device__ __forceinline__ u32 pack_bf2(float a, float b) {
  u32 ua = __builtin_bit_cast(u32, a) + 0x8000u;
  u32 ub = __builtin_bit_cast(u32, b) + 0x8000u;
  return __builtin_amdgcn_perm(ua, ub, 0x07060302u);
}

// async global->LDS, 16B per lane. LDS dest must be wave-uniform base + lane*16.
__device__ __forceinline__ void gload_lds16(const void* g, void* l) {
  __builtin_amdgcn_global_load_lds(
      (const __attribute__((address_space(1))) void*)g,
      (__attribute__((address_space(3))) void*)l, 16, 0, 0);
}

// ---- prep kernels ----------------------------------------------------------

// X fp32 [8192][1024] -> bf16
__global__ void cvt_x(const float* __restrict__ src, u16* __restrict__ dst) {
  int i = blockIdx.x * 256 + threadIdx.x;
  float4_t f = ((const float4_t*)src)[i];
  ushort4_t u;
  u.x = f2bf(f.x); u.y = f2bf(f.y); u.z = f2bf(f.z); u.w = f2bf(f.w);
  ((ushort4_t*)dst)[i] = u;
}

// coalesced LDS-tiled transpose+cvt: W fp32 [K][N] -> bf16 [N][K].
__global__ __launch_bounds__(256) void transpose_cvt4(
    const float* __restrict__ wq, const float* __restrict__ wk,
    const float* __restrict__ wv, const float* __restrict__ wo,
    u16* __restrict__ qk, u16* __restrict__ vt, u16* __restrict__ ot, float sc) {
  __shared__ float T[64][65];
  const int which = blockIdx.z;
  const float* s = (which == 0) ? wq : (which == 1) ? wk : (which == 2) ? wv : wo;
  u16* d = (which == 0) ? qk : (which == 1) ? (qk + (1u << 20)) : (which == 2) ? vt : ot;
  const float scale = (which == 0) ? sc : 1.f;
  const int n0 = blockIdx.x * 64, k0 = blockIdx.y * 64;
  const int c = threadIdx.x & 63, rg = threadIdx.x >> 6;
  for (int i = 0; i < 16; ++i) {
    int r = i * 4 + rg;
    T[r][c] = s[(k0 + r) * 1024 + n0 + c];
  }
  __syncthreads();
  for (int i = 0; i < 16; ++i) {
    int r = i * 4 + rg;
    d[(n0 + r) * 1024 + k0 + c] = f2bf(T[c][r] * scale);
  }
}

// ---- bf16 MFMA GEMM: C[m][n] = sum_k A[m][k] * Bt[n][k] --------------------
template <int MODE>
__global__ __launch_bounds__(256) void gemm_bt(
    const u16* __restrict__ A, const u16* __restrict__ Bt, void* __restrict__ Cv,
    const float* __restrict__ bias, int K, int lda, int ldb, int ldc) {
  __shared__ u16 As[2][128 * 32];
  __shared__ u16 Bs[2][128 * 32];
  const int tid = threadIdx.x;
  const int w = tid >> 6, l = tid & 63, quad = l >> 4, l16 = l & 15;
  const int wm = w >> 1, wn = w & 1;
  const size_t m0 = (size_t)blockIdx.y * 128, n0 = (size_t)blockIdx.x * 128;

  floatx4 acc[4][4];
  for (int i = 0; i < 4; ++i)
    for (int j = 0; j < 4; ++j) acc[i][j] = (floatx4){0.f, 0.f, 0.f, 0.f};

  auto stage = [&](int k0, int buf) {
    for (int i = 0; i < 2; ++i) {
      int c = i * 256 + tid;
      int row = c >> 2, off = (c & 3) * 8;
      gload_lds16(A + (m0 + row) * (size_t)lda + k0 + off, &As[buf][c * 8]);
      gload_lds16(Bt + (n0 + row) * (size_t)ldb + k0 + off, &Bs[buf][c * 8]);
    }
  };

  const int nk = K >> 5;
  stage(0, 0);
  __syncthreads();

  for (int ki = 0; ki < nk; ++ki) {
    const int buf = ki & 1;
    if (ki + 1 < nk) stage((ki + 1) << 5, buf ^ 1);

    short8 a[4], bb[4];
    for (int im = 0; im < 4; ++im)
      a[im] = *(const short8*)&As[buf][(wm * 64 + im * 16 + l16) * 32 + quad * 8];
    for (int in = 0; in < 4; ++in)
      bb[in] = *(const short8*)&Bs[buf][(wn * 64 + in * 16 + l16) * 32 + quad * 8];
    for (int im = 0; im < 4; ++im)
      for (int in = 0; in < 4; ++in)
        acc[im][in] = __builtin_amdgcn_mfma_f32_16x16x32_bf16(a[im], bb[in], acc[im][in], 0, 0, 0);

    __syncthreads();
  }

  for (int im = 0; im < 4; ++im)
    for (int in = 0; in < 4; ++in) {
      size_t r0 = m0 + wm * 64 + im * 16 + quad * 4;
      size_t col = n0 + wn * 64 + in * 16 + l16;
      float bv = (MODE == 1) ? bias[col] : 0.f;
      for (int r = 0; r < 4; ++r) {
        float val = acc[im][in][r] + bv;
        if (MODE == 0)
          ((u16*)Cv)[(r0 + r) * (size_t)ldc + col] = f2bf(val);
        else
          ((float*)Cv)[(r0 + r) * (size_t)ldc + col] = val;
      }
    }
}

// ---- flash attention (causal, S^T form, registered P, paired q-tiles) ------
// grid (64 bh, 8 p). Block handles qt = 15-p then qt = p: uniform 34 tiles.
// 256 thr = 4 waves; wave owns 32 q (2 x 16 frags) of the 128-q tile.
// QK: bf16 [8192][2048] (Q pre-scaled cols 0..1023, K cols 1024..2047).
// Vt: bf16 [1024][8192]. ctx: bf16 [8192][1024].
// S^T C-layout (col=l16=q, row=quad*4+r=kpos) IS the B-operand layout of
// 16x16x16 MFMA (k=quad*4+j) -> P stays in registers; PV: A=V^T from LDS.
// Swizzle: byte(row,col2B) = row*128 + ((2*col) ^ ((row&7)<<4)).
__global__ __launch_bounds__(256, 2) void flash_attn(
    const u16* __restrict__ QK, const u16* __restrict__ Vt, u16* __restrict__ ctx) {
  __shared__ u16 Ks[2][64 * 64];
  __shared__ u16 Vs[2][64 * 64];

  const int tid = threadIdx.x;
  const int w = tid >> 6, l = tid & 63, quad = l >> 4, l16 = l & 15;
  const int bh = blockIdx.x, p = blockIdx.y;
  const int b = bh >> 4, h = bh & 15;
  const int xr = (l16 & 7) << 4;

  const int qtA = 15 - p, qtB = p;          // long segment first
  const int nktA = 2 * qtA + 2, ntot = nktA + 2 * qtB + 2;   // = 34

  auto stage = [&](int kt, int buf) {
    for (int i = 0; i < 2; ++i) {
      int c = i * 256 + tid;
      int row = c >> 3, scol = ((c & 7) ^ (row & 7)) << 3;
      gload_lds16(QK + (size_t)(b * 2048 + kt * 64 + row) * 2048 + 1024 + h * 64 + scol,
                  &Ks[buf][c * 8]);
      gload_lds16(Vt + (size_t)(h * 64 + row) * 8192 + b * 2048 + kt * 64 + scol,
                  &Vs[buf][c * 8]);
    }
  };

  short8 aq[2][2];
  floatx4 o[2][4];
  float lsum[2];

  auto load_q = [&](int q0w) {
    for (int qf = 0; qf < 2; ++qf) {
      const size_t base = (size_t)(b * 2048 + q0w + qf * 16 + l16) * 2048 + h * 64 + quad * 8;
      aq[qf][0] = *(const short8*)(QK + base);
      aq[qf][1] = *(const short8*)(QK + base + 32);
    }
    for (int qf = 0; qf < 2; ++qf) {
      lsum[qf] = 0.f;
      for (int df = 0; df < 4; ++df) o[qf][df] = (floatx4){0.f, 0.f, 0.f, 0.f};
    }
  };

  auto epilogue = [&](int q0w) {
    for (int qf = 0; qf < 2; ++qf) {
      float t = lsum[qf];
      t += __shfl_xor(t, 16, 64);
      t += __shfl_xor(t, 32, 64);
      float inv = __builtin_amdgcn_rcpf(t);
      // o^T: lane q = l16, d = df*16 + quad*4 + r  -> in-lane normalize
      size_t row = (size_t)(b * 2048 + q0w + qf * 16 + l16);
      for (int df = 0; df < 4; ++df) {
        ushort4_t st;
        for (int r = 0; r < 4; ++r) st[r] = f2bf(o[qf][df][r] * inv);
        *(ushort4_t*)(ctx + row * 1024 + h * 64 + df * 16 + quad * 4) = st;
      }
    }
  };

  int q0w = qtA * 128 + w * 32;
  int ktmax_w = (q0w + 31) >> 6;
  load_q(q0w);
  stage(0, 0);
  __syncthreads();

  for (int t = 0; t < ntot; ++t) {
    const int buf = t & 1;
    const int kt = (t < nktA) ? t : t - nktA;
    if (t + 1 < ntot) {
      int tn = t + 1;
      stage((tn < nktA) ? tn : tn - nktA, buf ^ 1);
    }

    if (kt <= ktmax_w) {
      const bool need_mask = (kt == ktmax_w);

      short8 ka[4][2];
      for (int nf = 0; nf < 4; ++nf) {
        const char* kb = (const char*)&Ks[buf][0] + (nf * 16 + l16) * 128;
        ka[nf][0] = *(const short8*)(kb + ((quad * 16) ^ xr));
        ka[nf][1] = *(const short8*)(kb + ((64 + quad * 16) ^ xr));
      }
      // V^T A-frags for K=16 MFMA: va[kchunk][df], lane holds Vs[d][kchunk*16+quad*4+j]
      short4_t va[4][4];
      for (int df = 0; df < 4; ++df) {
        const char* vb = (const char*)&Vs[buf][0] + (df * 16 + l16) * 128;
        for (int nf = 0; nf < 4; ++nf)
          va[nf][df] = *(const short4_t*)(vb + ((nf * 32 + quad * 8) ^ xr));
      }

      for (int qf = 0; qf < 2; ++qf) {
        floatx4 s[4];
        for (int nf = 0; nf < 4; ++nf) s[nf] = (floatx4){0.f, 0.f, 0.f, 0.f};
        for (int nf = 0; nf < 4; ++nf) {
          s[nf] = __builtin_amdgcn_mfma_f32_16x16x32_bf16(ka[nf][0], aq[qf][0], s[nf], 0, 0, 0);
          s[nf] = __builtin_amdgcn_mfma_f32_16x16x32_bf16(ka[nf][1], aq[qf][1], s[nf], 0, 0, 0);
        }
        if (need_mask) {
          int qpos = q0w + qf * 16 + l16;
          for (int nf = 0; nf < 4; ++nf)
            for (int r = 0; r < 4; ++r) {
              int kpos = kt * 64 + nf * 16 + quad * 4 + r;
              if (kpos > qpos) s[nf][r] = -1e30f;
            }
        }
        for (int nf = 0; nf < 4; ++nf) {
          float p0 = __builtin_amdgcn_exp2f(s[nf][0]);
          float p1 = __builtin_amdgcn_exp2f(s[nf][1]);
          float p2 = __builtin_amdgcn_exp2f(s[nf][2]);
          float p3 = __builtin_amdgcn_exp2f(s[nf][3]);
          lsum[qf] += (p0 + p1) + (p2 + p3);
          uint2_t pk;
          pk.x = pack_bf2(p1, p0);   // lo16 = p0 (j=0), hi = p1
          pk.y = pack_bf2(p3, p2);
          short4_t pb = __builtin_bit_cast(short4_t, pk);  // B-frag of 16x16x16
          for (int df = 0; df < 4; ++df)
            o[qf][df] = __builtin_amdgcn_mfma_f32_16x16x16bf16_1k(va[nf][df], pb, o[qf][df], 0, 0, 0);
        }
      }
    }
    __syncthreads();

    if (t == nktA - 1) {          // segment boundary: finish qtA, start qtB
      epilogue(q0w);
      q0w = qtB * 128 + w * 32;
      ktmax_w = (q0w + 31) >> 6;
      load_q(q0w);
    }
  }
  epilogue(q0w);
}

// ---- launch ----------------------------------------------------------------

extern "C" void kernel_launch(void* const* d_in, const int* in_sizes, int n_in,
                              void* d_out, int out_size, void* d_ws, size_t ws_size,
                              hipStream_t stream) {
  const float* X  = (const float*)d_in[0];
  const float* Wq = (const float*)d_in[1];
  const float* Wk = (const float*)d_in[2];
  const float* Wv = (const float*)d_in[3];
  const float* Wo = (const float*)d_in[4];
  const float* bo = (const float*)d_in[5];

  char* ws = (char*)d_ws;
  u16* Xb   = (u16*)(ws);                  // 16 MiB; later overwritten with ctx
  u16* WqkT = (u16*)(ws + (16u << 20));    // 4 MiB: [Wq^T(scaled) ; Wk^T]
  u16* WvT  = (u16*)(ws + (20u << 20));    // 2 MiB
  u16* WoT  = (u16*)(ws + (22u << 20));    // 2 MiB
  u16* QKb  = (u16*)(ws + (24u << 20));    // 32 MiB: [8192][2048]
  u16* Vt   = (u16*)(ws + (56u << 20));    // 16 MiB: [1024][8192]

  const float SC = 0.125f * 1.44269504088896340736f;  // 1/sqrt(64) * log2(e)

  cvt_x<<<8192, 256, 0, stream>>>(X, Xb);
  transpose_cvt4<<<dim3(16, 16, 4), 256, 0, stream>>>(Wq, Wk, Wv, Wo, WqkT, WvT, WoT, SC);

  // [Q K] = Xb @ [Wq Wk] : [8192][2048]
  gemm_bt<0><<<dim3(16, 64), 256, 0, stream>>>(Xb, WqkT, QKb, nullptr, 1024, 1024, 1024, 2048);
  // Vt = (Xb @ Wv)^T : [1024][8192]
  gemm_bt<0><<<dim3(64, 8), 256, 0, stream>>>(WvT, Xb, Vt, nullptr, 1024, 1024, 1024, 8192);

  // causal flash attention (paired q-tiles); ctx overwrites Xb
  flash_attn<<<dim3(64, 8), 256, 0, stream>>>(QKb, Vt, Xb);

  // out = ctx @ Wo + bo : fp32
  gemm_bt<1><<<dim3(8, 64), 256, 0, stream>>>(Xb, WoT, (float*)d_out, bo, 1024, 1024, 1024, 1024);
}